// Round 15
// baseline (988.494 us; speedup 1.0000x reference)
//
#include <hip/hip_runtime.h>
#include <stdint.h>

#define T_    16
#define N_    2048
#define CAP_  96

typedef float v4 __attribute__((ext_vector_type(4)));
typedef float f32x4 __attribute__((ext_vector_type(4)));
typedef _Float16 f16x8 __attribute__((ext_vector_type(8)));

__device__ inline float frcp(float x){
#if __has_builtin(__builtin_amdgcn_rcpf)
  return __builtin_amdgcn_rcpf(x);
#else
  return 1.0f / x;
#endif
}
__device__ inline float fsig(float x){ return frcp(1.0f + __expf(-x)); }

// ---------------------------------------------------------------- mask build + cnt zero
__global__ __launch_bounds__(256) void k_mask(const uint8_t* __restrict__ ego_raw,
                                              float* __restrict__ m,
                                              int* __restrict__ cnt){
  __shared__ int s_int01, s_f01;
  const int tid = threadIdx.x;
  if (tid == 0){ s_int01 = 1; s_f01 = 1; }
  __syncthreads();
  const uint32_t* w = (const uint32_t*)ego_raw;
  int int01 = 1, f01 = 1;
  for (int i = tid; i < 8192; i += 256){
    uint32_t v = w[i];
    int01 &= (v <= 1u);
    f01   &= (v == 0u) || (v == 0x3F800000u);
  }
  if (!int01) atomicAnd(&s_int01, 0);
  if (!f01)   atomicAnd(&s_f01, 0);
  __syncthreads();
  const int mode = s_int01 ? 0 : (s_f01 ? 1 : 2); // 0:int32 1:f32 2:byte
  const int base = blockIdx.x * 2048;
  for (int q = tid; q < 2048; q += 256){
    int i = base + q;
    int t = i >> 11, n = i & 2047, b = n >> 8, j = n & 255;
    int src = (b*T_ + t)*256 + j;
    float val;
    if (mode == 0)      val = (((const int32_t*)ego_raw)[src] != 0)   ? 1.f : 0.f;
    else if (mode == 1) val = (((const float*)ego_raw)[src]  != 0.f)  ? 1.f : 0.f;
    else                val = (ego_raw[src] != 0)                     ? 1.f : 0.f;
    m[i] = val;
    cnt[i] = 0;
  }
}

// ---------------------------------------------------------------- masked sparsify (2048 blocks, 16 rows each)
__global__ __launch_bounds__(256) void k_sparsify(const float* __restrict__ adj,
                                                  const float* __restrict__ m,
                                                  int* __restrict__ cnt,
                                                  uint16_t* __restrict__ idx){
  const int bx = blockIdx.x;           // 2048 blocks
  const int t  = bx >> 7;              // 0..15
  const int sg = bx & 127;             // 0..127, 16 s-rows each
  const int tid = threadIdx.x;
  const int lane = tid & 63;
  const int tcol = t << 11;
  const float4* base4 = (const float4*)(adj + ((size_t)t << 22));
  const int d0a = tid << 2;            // ii=0 cols
  const int d0b = (256 + tid) << 2;    // ii=1 cols
  const float4 ma = *(const float4*)(m + tcol + d0a);
  const float4 mb = *(const float4*)(m + tcol + d0b);
  float mrow = (lane < 16) ? m[tcol + (sg << 4) + lane] : 0.f;
  const unsigned long long live = __ballot(mrow != 0.f) & 0xFFFFull;
  for (int sr = 0; sr < 16; sr++){
    if (!((live >> sr) & 1ull)) continue;          // dead source: scalar skip
    int s = (sg << 4) + sr;
    const float4* row4 = base4 + ((size_t)s << 9);
    float4 va = row4[tid];
    float4 vb = row4[256 + tid];
    if (va.x != 0.f && ma.x != 0.f){ int p = atomicAdd(&cnt[tcol+d0a  ],1); if (p<CAP_) idx[(size_t)(tcol+d0a  )*CAP_+p]=(uint16_t)s; }
    if (va.y != 0.f && ma.y != 0.f){ int p = atomicAdd(&cnt[tcol+d0a+1],1); if (p<CAP_) idx[(size_t)(tcol+d0a+1)*CAP_+p]=(uint16_t)s; }
    if (va.z != 0.f && ma.z != 0.f){ int p = atomicAdd(&cnt[tcol+d0a+2],1); if (p<CAP_) idx[(size_t)(tcol+d0a+2)*CAP_+p]=(uint16_t)s; }
    if (va.w != 0.f && ma.w != 0.f){ int p = atomicAdd(&cnt[tcol+d0a+3],1); if (p<CAP_) idx[(size_t)(tcol+d0a+3)*CAP_+p]=(uint16_t)s; }
    if (vb.x != 0.f && mb.x != 0.f){ int p = atomicAdd(&cnt[tcol+d0b  ],1); if (p<CAP_) idx[(size_t)(tcol+d0b  )*CAP_+p]=(uint16_t)s; }
    if (vb.y != 0.f && mb.y != 0.f){ int p = atomicAdd(&cnt[tcol+d0b+1],1); if (p<CAP_) idx[(size_t)(tcol+d0b+1)*CAP_+p]=(uint16_t)s; }
    if (vb.z != 0.f && mb.z != 0.f){ int p = atomicAdd(&cnt[tcol+d0b+2],1); if (p<CAP_) idx[(size_t)(tcol+d0b+2)*CAP_+p]=(uint16_t)s; }
    if (vb.w != 0.f && mb.w != 0.f){ int p = atomicAdd(&cnt[tcol+d0b+3],1); if (p<CAP_) idx[(size_t)(tcol+d0b+3)*CAP_+p]=(uint16_t)s; }
  }
}

// ---------------------------------------------------------------- FUSED layer1 + v2 (dinv inlined from cnt)
__global__ __launch_bounds__(256) void k_gcn1v2(const float* __restrict__ x,
                                                const float* __restrict__ W1,
                                                const float* __restrict__ b1,
                                                const float* __restrict__ W2,
                                                const int* __restrict__ cnt,
                                                const uint16_t* __restrict__ idx,
                                                const float* __restrict__ m,
                                                float* __restrict__ v2){
  __shared__ float h1s[256];            // 4 cols × 64
  const int col4 = threadIdx.x >> 6;
  const int col = blockIdx.x*4 + col4;
  const int lane = threadIdx.x & 63;
  const int craw = cnt[col];
  int c = craw; if (c > CAP_) c = CAP_;
  const float dc = (m[col] > 0.5f) ? rsqrtf(1.0f + (float)craw) : 0.f;
  const int tbase = col & ~2047;
  const uint16_t* lst = idx + (size_t)col*CAP_;
  const float w1a = W1[lane], w1b = W1[64 + lane];
  const float2* x2 = (const float2*)x;
  float2 xs = x2[col];
  float acc = dc*(xs.x*w1a + xs.y*w1b);            // self-loop
  int i = 0;
  for (; i + 4 <= c; i += 4){
    ushort4 s4 = *(const ushort4*)(lst + i);
    int sa = tbase+s4.x, sb = tbase+s4.y, sc = tbase+s4.z, sd = tbase+s4.w;
    float da = rsqrtf(1.0f + (float)cnt[sa]);      // listed neighbors are live
    float db = rsqrtf(1.0f + (float)cnt[sb]);
    float dcc= rsqrtf(1.0f + (float)cnt[sc]);
    float dd = rsqrtf(1.0f + (float)cnt[sd]);
    float2 xa = x2[sa], xb = x2[sb], xc = x2[sc], xd = x2[sd];
    acc += da*(xa.x*w1a + xa.y*w1b) + db*(xb.x*w1a + xb.y*w1b)
         + dcc*(xc.x*w1a + xc.y*w1b) + dd*(xd.x*w1a + xd.y*w1b);
  }
  for (; i < c; i++){
    int s = tbase + lst[i];
    float ds = rsqrtf(1.0f + (float)cnt[s]);
    float2 xv = x2[s];
    acc += ds*(xv.x*w1a + xv.y*w1b);
  }
  float y = dc*acc + b1[lane];
  h1s[threadIdx.x] = fmaxf(y, 0.f);
  __syncthreads();
  const float* hrow = h1s + col4*64;               // broadcast LDS reads
  float s = 0.f;
  #pragma unroll 8
  for (int h = 0; h < 64; h++) s += hrow[h]*W2[h*64 + lane];
  v2[(size_t)col*64 + lane] = dc*s;
}

// ---------------------------------------------------------------- FUSED layer2 agg + lstmpre (dinv inlined; true domain)
__global__ __launch_bounds__(256) void k_agg2pre(const float* __restrict__ v,
                                                 const int* __restrict__ cnt,
                                                 const uint16_t* __restrict__ idx,
                                                 const float* __restrict__ m,
                                                 const float* __restrict__ b2,
                                                 const float* __restrict__ Wih,
                                                 const float* __restrict__ bih,
                                                 const float* __restrict__ bhh,
                                                 float* __restrict__ P4){
  __shared__ float h2s[256];            // 4 cols × 64
  const int col4 = threadIdx.x >> 6;
  const int col = blockIdx.x*4 + col4;
  const int lane = threadIdx.x & 63;
  const int craw = cnt[col];
  int c = craw; if (c > CAP_) c = CAP_;
  const float mc = m[col];
  const float dc = (mc > 0.5f) ? rsqrtf(1.0f + (float)craw) : 0.f;
  const int tbase = col & ~2047;
  const uint16_t* lst = idx + (size_t)col*CAP_;
  float acc = v[(size_t)col*64 + lane];            // self-loop
  int i = 0;
  for (; i + 4 <= c; i += 4){
    ushort4 s4 = *(const ushort4*)(lst + i);
    float a0 = v[((size_t)tbase + s4.x)*64 + lane];
    float a1 = v[((size_t)tbase + s4.y)*64 + lane];
    float a2 = v[((size_t)tbase + s4.z)*64 + lane];
    float a3 = v[((size_t)tbase + s4.w)*64 + lane];
    acc += (a0 + a1) + (a2 + a3);
  }
  for (; i < c; i++) acc += v[((size_t)tbase + lst[i])*64 + lane];
  float y = dc*acc + b2[lane];
  h2s[threadIdx.x] = mc*y;
  __syncthreads();
  #pragma unroll
  for (int o = threadIdx.x; o < 512; o += 256){
    const int cc = o >> 7;                         // 0..3
    const int j  = o & 127;
    const int tn = blockIdx.x*4 + cc;
    const v4* hrow = (const v4*)(h2s + cc*64);     // broadcast LDS b128 reads
    const v4* wr = (const v4*)(Wih + j*64);
    float a0 = bih[j] + bhh[j], a1 = 0.f, a2 = 0.f, a3 = 0.f;
    #pragma unroll
    for (int q = 0; q < 16; q++){
      v4 hv = hrow[q], wv = wr[q];
      a0 = fmaf(wv.x, hv.x, a0);
      a1 = fmaf(wv.y, hv.y, a1);
      a2 = fmaf(wv.z, hv.z, a2);
      a3 = fmaf(wv.w, hv.w, a3);
    }
    const int dst = (j & 31)*4 + (j >> 5);         // interleaved {i,f,g,o}
    P4[(size_t)tn*128 + dst] = (a0 + a1) + (a2 + a3);
  }
}

// ---------------------------------------------------------------- LSTM scan: 16 chains, 1 wave each
// R14 structure, unroll 2→4 (main loop 2044 = 4×511; 2 prefetch tails + 2
// plain tails). More cross-iteration interleave for the serial-chain stalls.
__global__ __attribute__((amdgpu_flat_work_group_size(64,64), amdgpu_waves_per_eu(1,1)))
void k_lstm(const float* __restrict__ P4,
            const float* __restrict__ Whh,
            _Float16* __restrict__ L16){
  const int t = blockIdx.x;       // chain 0..15
  const int l = threadIdx.x;      // 0..63
  const int c4 = l & 15, q = l >> 4;
  const int j = l & 31;
#define LB(B) f16x8 b##B; { const float* wr = Whh + (size_t)(16*B + c4)*32 + 8*q; \
    f16x8 tmp; tmp[0]=(_Float16)wr[0]; tmp[1]=(_Float16)wr[1]; tmp[2]=(_Float16)wr[2]; \
    tmp[3]=(_Float16)wr[3]; tmp[4]=(_Float16)wr[4]; tmp[5]=(_Float16)wr[5]; \
    tmp[6]=(_Float16)wr[6]; tmp[7]=(_Float16)wr[7]; b##B = tmp; } asm("" : "+v"(b##B));
  LB(0) LB(1) LB(2) LB(3) LB(4) LB(5) LB(6) LB(7)
#undef LB
  __shared__ __align__(16) _Float16 hs[64];
  hs[l] = (_Float16)0.f;
  const float4* Pt = (const float4*)P4 + (size_t)t*N_*32 + j;
  _Float16* Lt = L16 + (size_t)t*N_*64;
  float c = 0.f;
  const f32x4 zero = {0.f, 0.f, 0.f, 0.f};
  const bool hiq = (l & 16) != 0;
  float4 p0 = Pt[0], p1 = Pt[32];

  auto step = [&](int n, bool prefetch) __attribute__((always_inline)) {
    float4 cur = p0; p0 = p1;
    if (prefetch) p1 = Pt[(size_t)(n + 2)*32];
    f16x8 af = *(const f16x8*)(hs + 8*q);          // ds_read_b128 (broadcast)
    f32x4 d0 = __builtin_amdgcn_mfma_f32_16x16x32_f16(af, b0, zero, 0, 0, 0);
    f32x4 d1 = __builtin_amdgcn_mfma_f32_16x16x32_f16(af, b1, zero, 0, 0, 0);
    f32x4 d2 = __builtin_amdgcn_mfma_f32_16x16x32_f16(af, b2, zero, 0, 0, 0);
    f32x4 d3 = __builtin_amdgcn_mfma_f32_16x16x32_f16(af, b3, zero, 0, 0, 0);
    f32x4 d4 = __builtin_amdgcn_mfma_f32_16x16x32_f16(af, b4, zero, 0, 0, 0);
    f32x4 d5 = __builtin_amdgcn_mfma_f32_16x16x32_f16(af, b5, zero, 0, 0, 0);
    f32x4 d6 = __builtin_amdgcn_mfma_f32_16x16x32_f16(af, b6, zero, 0, 0, 0);
    f32x4 d7 = __builtin_amdgcn_mfma_f32_16x16x32_f16(af, b7, zero, 0, 0, 0);
    float gi = cur.x + (hiq ? d1[0] : d0[0]);
    float gf = cur.y + (hiq ? d3[0] : d2[0]);
    float gg = cur.z + (hiq ? d5[0] : d4[0]);
    float go = cur.w + (hiq ? d7[0] : d6[0]);
    float iv = fsig(gi);
    float fv = fsig(gf);
    float gv = fmaf(2.0f, fsig(2.0f*gg), -1.0f);   // tanh
    float ov = fsig(go);
    c = fmaf(fv, c, iv*gv);
    float th = fmaf(2.0f, fsig(2.0f*c), -1.0f);    // tanh(c)
    float hn = ov*th;
    _Float16 hf = (_Float16)hn;
    hs[l] = hf;                                    // conflict-free ds_write_b16
    Lt[n*64 + l] = hf;                             // full-wave 128B f16 store
  };

  #pragma unroll 4
  for (int n = 0; n < N_ - 4; n++) step(n, true);  // 2044 = 4×511
  step(N_ - 4, true);
  step(N_ - 3, true);
  step(N_ - 2, false);
  step(N_ - 1, false);
}

// ---------------------------------------------------------------- FUSED score + softmax attention pool (f16 L)
__global__ __launch_bounds__(256) void k_attn(const _Float16* __restrict__ L16,
                                              const float* __restrict__ Wa,
                                              float* __restrict__ out){
  __shared__ float sLDS[128];           // 8 nodes × 16 scores
  const int tid = threadIdx.x;
  const int sub = tid >> 5, k = tid & 31;
  const int n = blockIdx.x*8 + sub;
  if (k < 16){
    const int t = k;
    const f16x8* row = (const f16x8*)(L16 + ((size_t)(t << 11) + n)*64);
    const float4* wa4 = (const float4*)Wa;
    float s = 0.f;
    #pragma unroll
    for (int qq = 0; qq < 4; qq++){
      f16x8 hv = row[qq];
      float4 w0 = wa4[2*qq], w1 = wa4[2*qq+1];
      s += (float)hv[0]*w0.x + (float)hv[1]*w0.y + (float)hv[2]*w0.z + (float)hv[3]*w0.w
         + (float)hv[4]*w1.x + (float)hv[5]*w1.y + (float)hv[6]*w1.z + (float)hv[7]*w1.w;
    }
    sLDS[sub*16 + t] = s;
  }
  __syncthreads();
  float sc[16]; float mx = -1e30f;
  #pragma unroll
  for (int t = 0; t < 16; t++){ float v = sLDS[sub*16 + t]; sc[t] = v; mx = fmaxf(mx, v); }
  float sum = 0.f;
  #pragma unroll
  for (int t = 0; t < 16; t++){ float e = __expf(sc[t] - mx); sc[t] = e; sum += e; }
  const float inv = frcp(sum);
  float acc = 0.f;
  #pragma unroll
  for (int t = 0; t < 16; t++) acc += sc[t]*(float)L16[((size_t)(t << 11) + n)*64 + k];
  out[n*32 + k] = acc*inv;
}

// ---------------------------------------------------------------- launch
extern "C" void kernel_launch(void* const* d_in, const int* in_sizes, int n_in,
                              void* d_out, int out_size, void* d_ws, size_t ws_size,
                              hipStream_t stream){
  (void)in_sizes; (void)n_in; (void)out_size; (void)ws_size;
  const float*   x   = (const float*)d_in[0];
  const float*   adj = (const float*)d_in[1];
  const uint8_t* ego = (const uint8_t*)d_in[2];
  const float*   W1  = (const float*)d_in[3];
  const float*   b1  = (const float*)d_in[4];
  const float*   W2  = (const float*)d_in[5];
  const float*   b2  = (const float*)d_in[6];
  const float*   Wih = (const float*)d_in[7];
  const float*   Whh = (const float*)d_in[8];
  const float*   bih = (const float*)d_in[9];
  const float*   bhh = (const float*)d_in[10];
  const float*   Wa  = (const float*)d_in[11];
  // d_in[12] = ba: softmax is shift-invariant, unused
  float* out = (float*)d_out;
  char* ws = (char*)d_ws;

  float*     m    = (float*)(ws);                  // 128 KB
  int*       cnt  = (int*)  (ws + 262144);         // 128 KB
  uint16_t*  idx  = (uint16_t*)(ws + 393216);      // 6 MB   (end 6,684,672)
  float*     v2   = (float*)(ws + 6684672);        // 8 MB   (v2; later reused as L16)
  float*     P4   = (float*)(ws + 15073280);       // 16 MB  (end 31,850,496)
  _Float16*  L16  = (_Float16*)v2;                 // v2 dead after k_agg2pre (4 MB)

  k_mask    <<<16,   256, 0, stream>>>(ego, m, cnt);
  k_sparsify<<<2048, 256, 0, stream>>>(adj, m, cnt, idx);
  k_gcn1v2  <<<8192, 256, 0, stream>>>(x, W1, b1, W2, cnt, idx, m, v2);
  k_agg2pre <<<8192, 256, 0, stream>>>(v2, cnt, idx, m, b2, Wih, bih, bhh, P4);
  k_lstm    <<<16,   64,  0, stream>>>(P4, Whh, L16);
  k_attn    <<<256,  256, 0, stream>>>(L16, Wa, out);
}

// Round 16
// 935.168 us; speedup vs baseline: 1.0570x; 1.0570x over previous
//
#include <hip/hip_runtime.h>
#include <stdint.h>

#define T_    16
#define N_    2048
#define CAP_  96

typedef float v4 __attribute__((ext_vector_type(4)));
typedef float f32x4 __attribute__((ext_vector_type(4)));
typedef _Float16 f16x8 __attribute__((ext_vector_type(8)));

__device__ inline float frcp(float x){
#if __has_builtin(__builtin_amdgcn_rcpf)
  return __builtin_amdgcn_rcpf(x);
#else
  return 1.0f / x;
#endif
}
__device__ inline float fsig(float x){ return frcp(1.0f + __expf(-x)); }

// ---------------------------------------------------------------- mask build + cnt zero
__global__ __launch_bounds__(256) void k_mask(const uint8_t* __restrict__ ego_raw,
                                              float* __restrict__ m,
                                              int* __restrict__ cnt){
  __shared__ int s_int01, s_f01;
  const int tid = threadIdx.x;
  if (tid == 0){ s_int01 = 1; s_f01 = 1; }
  __syncthreads();
  const uint32_t* w = (const uint32_t*)ego_raw;
  int int01 = 1, f01 = 1;
  for (int i = tid; i < 8192; i += 256){
    uint32_t v = w[i];
    int01 &= (v <= 1u);
    f01   &= (v == 0u) || (v == 0x3F800000u);
  }
  if (!int01) atomicAnd(&s_int01, 0);
  if (!f01)   atomicAnd(&s_f01, 0);
  __syncthreads();
  const int mode = s_int01 ? 0 : (s_f01 ? 1 : 2); // 0:int32 1:f32 2:byte
  const int base = blockIdx.x * 2048;
  for (int q = tid; q < 2048; q += 256){
    int i = base + q;
    int t = i >> 11, n = i & 2047, b = n >> 8, j = n & 255;
    int src = (b*T_ + t)*256 + j;
    float val;
    if (mode == 0)      val = (((const int32_t*)ego_raw)[src] != 0)   ? 1.f : 0.f;
    else if (mode == 1) val = (((const float*)ego_raw)[src]  != 0.f)  ? 1.f : 0.f;
    else                val = (ego_raw[src] != 0)                     ? 1.f : 0.f;
    m[i] = val;
    cnt[i] = 0;
  }
}

// ---------------------------------------------------------------- masked sparsify (2048 blocks, 16 rows each)
__global__ __launch_bounds__(256) void k_sparsify(const float* __restrict__ adj,
                                                  const float* __restrict__ m,
                                                  int* __restrict__ cnt,
                                                  uint16_t* __restrict__ idx){
  const int bx = blockIdx.x;           // 2048 blocks
  const int t  = bx >> 7;              // 0..15
  const int sg = bx & 127;             // 0..127, 16 s-rows each
  const int tid = threadIdx.x;
  const int lane = tid & 63;
  const int tcol = t << 11;
  const float4* base4 = (const float4*)(adj + ((size_t)t << 22));
  const int d0a = tid << 2;            // ii=0 cols
  const int d0b = (256 + tid) << 2;    // ii=1 cols
  const float4 ma = *(const float4*)(m + tcol + d0a);
  const float4 mb = *(const float4*)(m + tcol + d0b);
  float mrow = (lane < 16) ? m[tcol + (sg << 4) + lane] : 0.f;
  const unsigned long long live = __ballot(mrow != 0.f) & 0xFFFFull;
  for (int sr = 0; sr < 16; sr++){
    if (!((live >> sr) & 1ull)) continue;          // dead source: scalar skip
    int s = (sg << 4) + sr;
    const float4* row4 = base4 + ((size_t)s << 9);
    float4 va = row4[tid];
    float4 vb = row4[256 + tid];
    if (va.x != 0.f && ma.x != 0.f){ int p = atomicAdd(&cnt[tcol+d0a  ],1); if (p<CAP_) idx[(size_t)(tcol+d0a  )*CAP_+p]=(uint16_t)s; }
    if (va.y != 0.f && ma.y != 0.f){ int p = atomicAdd(&cnt[tcol+d0a+1],1); if (p<CAP_) idx[(size_t)(tcol+d0a+1)*CAP_+p]=(uint16_t)s; }
    if (va.z != 0.f && ma.z != 0.f){ int p = atomicAdd(&cnt[tcol+d0a+2],1); if (p<CAP_) idx[(size_t)(tcol+d0a+2)*CAP_+p]=(uint16_t)s; }
    if (va.w != 0.f && ma.w != 0.f){ int p = atomicAdd(&cnt[tcol+d0a+3],1); if (p<CAP_) idx[(size_t)(tcol+d0a+3)*CAP_+p]=(uint16_t)s; }
    if (vb.x != 0.f && mb.x != 0.f){ int p = atomicAdd(&cnt[tcol+d0b  ],1); if (p<CAP_) idx[(size_t)(tcol+d0b  )*CAP_+p]=(uint16_t)s; }
    if (vb.y != 0.f && mb.y != 0.f){ int p = atomicAdd(&cnt[tcol+d0b+1],1); if (p<CAP_) idx[(size_t)(tcol+d0b+1)*CAP_+p]=(uint16_t)s; }
    if (vb.z != 0.f && mb.z != 0.f){ int p = atomicAdd(&cnt[tcol+d0b+2],1); if (p<CAP_) idx[(size_t)(tcol+d0b+2)*CAP_+p]=(uint16_t)s; }
    if (vb.w != 0.f && mb.w != 0.f){ int p = atomicAdd(&cnt[tcol+d0b+3],1); if (p<CAP_) idx[(size_t)(tcol+d0b+3)*CAP_+p]=(uint16_t)s; }
  }
}

// ---------------------------------------------------------------- FUSED layer1 + v2 (dinv inlined from cnt)
__global__ __launch_bounds__(256) void k_gcn1v2(const float* __restrict__ x,
                                                const float* __restrict__ W1,
                                                const float* __restrict__ b1,
                                                const float* __restrict__ W2,
                                                const int* __restrict__ cnt,
                                                const uint16_t* __restrict__ idx,
                                                const float* __restrict__ m,
                                                float* __restrict__ v2){
  __shared__ float h1s[256];            // 4 cols × 64
  const int col4 = threadIdx.x >> 6;
  const int col = blockIdx.x*4 + col4;
  const int lane = threadIdx.x & 63;
  const int craw = cnt[col];
  int c = craw; if (c > CAP_) c = CAP_;
  const float dc = (m[col] > 0.5f) ? rsqrtf(1.0f + (float)craw) : 0.f;
  const int tbase = col & ~2047;
  const uint16_t* lst = idx + (size_t)col*CAP_;
  const float w1a = W1[lane], w1b = W1[64 + lane];
  const float2* x2 = (const float2*)x;
  float2 xs = x2[col];
  float acc = dc*(xs.x*w1a + xs.y*w1b);            // self-loop
  int i = 0;
  for (; i + 4 <= c; i += 4){
    ushort4 s4 = *(const ushort4*)(lst + i);
    int sa = tbase+s4.x, sb = tbase+s4.y, sc = tbase+s4.z, sd = tbase+s4.w;
    float da = rsqrtf(1.0f + (float)cnt[sa]);      // listed neighbors are live
    float db = rsqrtf(1.0f + (float)cnt[sb]);
    float dcc= rsqrtf(1.0f + (float)cnt[sc]);
    float dd = rsqrtf(1.0f + (float)cnt[sd]);
    float2 xa = x2[sa], xb = x2[sb], xc = x2[sc], xd = x2[sd];
    acc += da*(xa.x*w1a + xa.y*w1b) + db*(xb.x*w1a + xb.y*w1b)
         + dcc*(xc.x*w1a + xc.y*w1b) + dd*(xd.x*w1a + xd.y*w1b);
  }
  for (; i < c; i++){
    int s = tbase + lst[i];
    float ds = rsqrtf(1.0f + (float)cnt[s]);
    float2 xv = x2[s];
    acc += ds*(xv.x*w1a + xv.y*w1b);
  }
  float y = dc*acc + b1[lane];
  h1s[threadIdx.x] = fmaxf(y, 0.f);
  __syncthreads();
  const float* hrow = h1s + col4*64;               // broadcast LDS reads
  float s = 0.f;
  #pragma unroll 8
  for (int h = 0; h < 64; h++) s += hrow[h]*W2[h*64 + lane];
  v2[(size_t)col*64 + lane] = dc*s;
}

// ---------------------------------------------------------------- FUSED layer2 agg + lstmpre (dinv inlined; true domain)
__global__ __launch_bounds__(256) void k_agg2pre(const float* __restrict__ v,
                                                 const int* __restrict__ cnt,
                                                 const uint16_t* __restrict__ idx,
                                                 const float* __restrict__ m,
                                                 const float* __restrict__ b2,
                                                 const float* __restrict__ Wih,
                                                 const float* __restrict__ bih,
                                                 const float* __restrict__ bhh,
                                                 float* __restrict__ P4){
  __shared__ float h2s[256];            // 4 cols × 64
  const int col4 = threadIdx.x >> 6;
  const int col = blockIdx.x*4 + col4;
  const int lane = threadIdx.x & 63;
  const int craw = cnt[col];
  int c = craw; if (c > CAP_) c = CAP_;
  const float mc = m[col];
  const float dc = (mc > 0.5f) ? rsqrtf(1.0f + (float)craw) : 0.f;
  const int tbase = col & ~2047;
  const uint16_t* lst = idx + (size_t)col*CAP_;
  float acc = v[(size_t)col*64 + lane];            // self-loop
  int i = 0;
  for (; i + 4 <= c; i += 4){
    ushort4 s4 = *(const ushort4*)(lst + i);
    float a0 = v[((size_t)tbase + s4.x)*64 + lane];
    float a1 = v[((size_t)tbase + s4.y)*64 + lane];
    float a2 = v[((size_t)tbase + s4.z)*64 + lane];
    float a3 = v[((size_t)tbase + s4.w)*64 + lane];
    acc += (a0 + a1) + (a2 + a3);
  }
  for (; i < c; i++) acc += v[((size_t)tbase + lst[i])*64 + lane];
  float y = dc*acc + b2[lane];
  h2s[threadIdx.x] = mc*y;
  __syncthreads();
  #pragma unroll
  for (int o = threadIdx.x; o < 512; o += 256){
    const int cc = o >> 7;                         // 0..3
    const int j  = o & 127;
    const int tn = blockIdx.x*4 + cc;
    const v4* hrow = (const v4*)(h2s + cc*64);     // broadcast LDS b128 reads
    const v4* wr = (const v4*)(Wih + j*64);
    float a0 = bih[j] + bhh[j], a1 = 0.f, a2 = 0.f, a3 = 0.f;
    #pragma unroll
    for (int q = 0; q < 16; q++){
      v4 hv = hrow[q], wv = wr[q];
      a0 = fmaf(wv.x, hv.x, a0);
      a1 = fmaf(wv.y, hv.y, a1);
      a2 = fmaf(wv.z, hv.z, a2);
      a3 = fmaf(wv.w, hv.w, a3);
    }
    const int dst = (j & 31)*4 + (j >> 5);         // interleaved {i,f,g,o}
    P4[(size_t)tn*128 + dst] = (a0 + a1) + (a2 + a3);
  }
}

// ---------------------------------------------------------------- LSTM scan: 16 chains, 1 wave each
// EXACT R14 (best measured: 409 µs). unroll 2 + split-loop prefetch (unroll 4
// regressed to 461 — register pressure across 4 in-flight iterations).
__global__ __attribute__((amdgpu_flat_work_group_size(64,64), amdgpu_waves_per_eu(1,1)))
void k_lstm(const float* __restrict__ P4,
            const float* __restrict__ Whh,
            _Float16* __restrict__ L16){
  const int t = blockIdx.x;       // chain 0..15
  const int l = threadIdx.x;      // 0..63
  const int c4 = l & 15, q = l >> 4;
  const int j = l & 31;
#define LB(B) f16x8 b##B; { const float* wr = Whh + (size_t)(16*B + c4)*32 + 8*q; \
    f16x8 tmp; tmp[0]=(_Float16)wr[0]; tmp[1]=(_Float16)wr[1]; tmp[2]=(_Float16)wr[2]; \
    tmp[3]=(_Float16)wr[3]; tmp[4]=(_Float16)wr[4]; tmp[5]=(_Float16)wr[5]; \
    tmp[6]=(_Float16)wr[6]; tmp[7]=(_Float16)wr[7]; b##B = tmp; } asm("" : "+v"(b##B));
  LB(0) LB(1) LB(2) LB(3) LB(4) LB(5) LB(6) LB(7)
#undef LB
  __shared__ __align__(16) _Float16 hs[64];
  hs[l] = (_Float16)0.f;
  const float4* Pt = (const float4*)P4 + (size_t)t*N_*32 + j;
  _Float16* Lt = L16 + (size_t)t*N_*64;
  float c = 0.f;
  const f32x4 zero = {0.f, 0.f, 0.f, 0.f};
  const bool hiq = (l & 16) != 0;
  float4 p0 = Pt[0], p1 = Pt[32];

  auto step = [&](int n, bool prefetch) __attribute__((always_inline)) {
    float4 cur = p0; p0 = p1;
    if (prefetch) p1 = Pt[(size_t)(n + 2)*32];
    f16x8 af = *(const f16x8*)(hs + 8*q);          // ds_read_b128 (broadcast)
    f32x4 d0 = __builtin_amdgcn_mfma_f32_16x16x32_f16(af, b0, zero, 0, 0, 0);
    f32x4 d1 = __builtin_amdgcn_mfma_f32_16x16x32_f16(af, b1, zero, 0, 0, 0);
    f32x4 d2 = __builtin_amdgcn_mfma_f32_16x16x32_f16(af, b2, zero, 0, 0, 0);
    f32x4 d3 = __builtin_amdgcn_mfma_f32_16x16x32_f16(af, b3, zero, 0, 0, 0);
    f32x4 d4 = __builtin_amdgcn_mfma_f32_16x16x32_f16(af, b4, zero, 0, 0, 0);
    f32x4 d5 = __builtin_amdgcn_mfma_f32_16x16x32_f16(af, b5, zero, 0, 0, 0);
    f32x4 d6 = __builtin_amdgcn_mfma_f32_16x16x32_f16(af, b6, zero, 0, 0, 0);
    f32x4 d7 = __builtin_amdgcn_mfma_f32_16x16x32_f16(af, b7, zero, 0, 0, 0);
    float gi = cur.x + (hiq ? d1[0] : d0[0]);
    float gf = cur.y + (hiq ? d3[0] : d2[0]);
    float gg = cur.z + (hiq ? d5[0] : d4[0]);
    float go = cur.w + (hiq ? d7[0] : d6[0]);
    float iv = fsig(gi);
    float fv = fsig(gf);
    float gv = fmaf(2.0f, fsig(2.0f*gg), -1.0f);   // tanh
    float ov = fsig(go);
    c = fmaf(fv, c, iv*gv);
    float th = fmaf(2.0f, fsig(2.0f*c), -1.0f);    // tanh(c)
    float hn = ov*th;
    _Float16 hf = (_Float16)hn;
    hs[l] = hf;                                    // conflict-free ds_write_b16
    Lt[n*64 + l] = hf;                             // full-wave 128B f16 store
  };

  #pragma unroll 2
  for (int n = 0; n < N_ - 2; n++) step(n, true);
  step(N_ - 2, false);
  step(N_ - 1, false);
}

// ---------------------------------------------------------------- FUSED score + softmax attention pool (f16 L)
__global__ __launch_bounds__(256) void k_attn(const _Float16* __restrict__ L16,
                                              const float* __restrict__ Wa,
                                              float* __restrict__ out){
  __shared__ float sLDS[128];           // 8 nodes × 16 scores
  const int tid = threadIdx.x;
  const int sub = tid >> 5, k = tid & 31;
  const int n = blockIdx.x*8 + sub;
  if (k < 16){
    const int t = k;
    const f16x8* row = (const f16x8*)(L16 + ((size_t)(t << 11) + n)*64);
    const float4* wa4 = (const float4*)Wa;
    float s = 0.f;
    #pragma unroll
    for (int qq = 0; qq < 4; qq++){
      f16x8 hv = row[qq];
      float4 w0 = wa4[2*qq], w1 = wa4[2*qq+1];
      s += (float)hv[0]*w0.x + (float)hv[1]*w0.y + (float)hv[2]*w0.z + (float)hv[3]*w0.w
         + (float)hv[4]*w1.x + (float)hv[5]*w1.y + (float)hv[6]*w1.z + (float)hv[7]*w1.w;
    }
    sLDS[sub*16 + t] = s;
  }
  __syncthreads();
  float sc[16]; float mx = -1e30f;
  #pragma unroll
  for (int t = 0; t < 16; t++){ float v = sLDS[sub*16 + t]; sc[t] = v; mx = fmaxf(mx, v); }
  float sum = 0.f;
  #pragma unroll
  for (int t = 0; t < 16; t++){ float e = __expf(sc[t] - mx); sc[t] = e; sum += e; }
  const float inv = frcp(sum);
  float acc = 0.f;
  #pragma unroll
  for (int t = 0; t < 16; t++) acc += sc[t]*(float)L16[((size_t)(t << 11) + n)*64 + k];
  out[n*32 + k] = acc*inv;
}

// ---------------------------------------------------------------- launch
extern "C" void kernel_launch(void* const* d_in, const int* in_sizes, int n_in,
                              void* d_out, int out_size, void* d_ws, size_t ws_size,
                              hipStream_t stream){
  (void)in_sizes; (void)n_in; (void)out_size; (void)ws_size;
  const float*   x   = (const float*)d_in[0];
  const float*   adj = (const float*)d_in[1];
  const uint8_t* ego = (const uint8_t*)d_in[2];
  const float*   W1  = (const float*)d_in[3];
  const float*   b1  = (const float*)d_in[4];
  const float*   W2  = (const float*)d_in[5];
  const float*   b2  = (const float*)d_in[6];
  const float*   Wih = (const float*)d_in[7];
  const float*   Whh = (const float*)d_in[8];
  const float*   bih = (const float*)d_in[9];
  const float*   bhh = (const float*)d_in[10];
  const float*   Wa  = (const float*)d_in[11];
  // d_in[12] = ba: softmax is shift-invariant, unused
  float* out = (float*)d_out;
  char* ws = (char*)d_ws;

  float*     m    = (float*)(ws);                  // 128 KB
  int*       cnt  = (int*)  (ws + 262144);         // 128 KB
  uint16_t*  idx  = (uint16_t*)(ws + 393216);      // 6 MB   (end 6,684,672)
  float*     v2   = (float*)(ws + 6684672);        // 8 MB   (v2; later reused as L16)
  float*     P4   = (float*)(ws + 15073280);       // 16 MB  (end 31,850,496)
  _Float16*  L16  = (_Float16*)v2;                 // v2 dead after k_agg2pre (4 MB)

  k_mask    <<<16,   256, 0, stream>>>(ego, m, cnt);
  k_sparsify<<<2048, 256, 0, stream>>>(adj, m, cnt, idx);
  k_gcn1v2  <<<8192, 256, 0, stream>>>(x, W1, b1, W2, cnt, idx, m, v2);
  k_agg2pre <<<8192, 256, 0, stream>>>(v2, cnt, idx, m, b2, Wih, bih, bhh, P4);
  k_lstm    <<<16,   64,  0, stream>>>(P4, Whh, L16);
  k_attn    <<<256,  256, 0, stream>>>(L16, Wa, out);
}